// Round 8
// baseline (217.984 us; speedup 1.0000x reference)
//
#include <hip/hip_runtime.h>

#define K_CODES 512
#define DIM 64
#define HW 1024
#define NVEC 65536
#define NREP 32

// Output offsets (flat concat, reference return order)
#define O0 0             // loss (1)
#define O1 1             // out_q NCHW (4194304)
#define O2 4194305       // perplexity (1)
#define O3 4194306       // idx as float (65536)
#define O4 4259842       // new_cs (512)
#define O5 4260354       // new_ema_w (32768)
#define O6 4293122       // new_embedding (32768)

// ws float layout:
// [0..512)              = ee (||e_k||^2)
// [512..16896)          = counts, 32 replicas x 512 (int)
// [16896..18944)        = per-tile loss partials (2048)
// [18944]               = n (0.99*sum(ema_cs) + 0.01*65536)
// [19200..1067776)      = dw, 32 replicas x 32768
// [1067776..)           = B-pack (98304 bf16, MFMA-frag order)
#define WS_EE   0
#define WS_CNT  512
#define WS_LOSS 16896
#define WS_N    18944
#define WS_DW   19200
#define WS_BP   1067776

typedef __bf16 bf16x8 __attribute__((ext_vector_type(8)));
typedef float  f32x4  __attribute__((ext_vector_type(4)));

union U2 { unsigned int u; unsigned short us[2]; __bf16 h[2]; };

__global__ void k0_init(const float* __restrict__ emb, const float* __restrict__ ema_cs,
                        float* __restrict__ wsf) {
    __shared__ float sn[256];
    const int b = blockIdx.x, t = threadIdx.x;
    if (b < 512) {
        #pragma unroll
        for (int i = 0; i < 8; ++i)                      // zero 32 dw replicas (2048 f/block)
            wsf[WS_DW + b * 2048 + i * 256 + t] = 0.0f;
    } else if (b == 512) {
        int* cnt = (int*)(wsf + WS_CNT);
        #pragma unroll
        for (int i = 0; i < 64; ++i) cnt[i * 256 + t] = 0;  // zero 32 cnt replicas
        sn[t] = ema_cs[t] + ema_cs[t + 256];
        __syncthreads();
        for (int s = 128; s > 0; s >>= 1) {
            if (t < s) sn[t] += sn[t + s];
            __syncthreads();
        }
        if (t == 0) wsf[WS_N] = 0.99f * sn[0] + 0.01f * 65536.0f;  // n (counts sum to NVEC)
    } else if (b < 515) {
        int k = (b - 513) * 256 + t;                     // 0..511
        const float* e = emb + k * DIM;
        float s = 0.0f;
        #pragma unroll
        for (int c = 0; c < DIM; ++c) s += e[c] * e[c];
        wsf[WS_EE + k] = s;                              // ||e_k||^2
    } else {
        // Pack bf16 3-way split of (-2*e) into MFMA B-fragment order:
        // frag(s, ntg, ks): lane l holds B^T[code = ntg*16 + (l&15)][c = ks*32 + (l>>4)*8 + j]
        int g = (b - 515) * 256 + t;                     // 0..98303
        int j    = g & 7;
        int lane = (g >> 3) & 63;
        int ks   = (g >> 9) & 1;
        int rest = g >> 10;                              // 0..95
        int ntg  = rest & 31;
        int s    = rest >> 5;                            // split 0..2
        int code = ntg * 16 + (lane & 15);
        int c    = ks * 32 + (lane >> 4) * 8 + j;
        float v = -2.0f * emb[code * DIM + c];
        __bf16 h0 = (__bf16)v;  float r1 = v  - (float)h0;
        __bf16 h1 = (__bf16)r1; float r2 = r1 - (float)h1;
        __bf16 hv = (s == 0) ? h0 : (s == 1 ? h1 : (__bf16)r2);
        ((__bf16*)(wsf + WS_BP))[g] = hv;
    }
}

// Macro: build bf16 3-split of 8 staged floats into xsp[BUF] + xxp[BUF].
#define BUILD_SPLITS(SV, BUF)                                                  \
    {                                                                          \
        float xxa = 0.0f;                                                      \
        _Pragma("unroll")                                                      \
        for (int it = 0; it < 4; ++it) {                                       \
            int cp = it * 8 + cp0;                                             \
            float v0 = SV[2 * it], v1 = SV[2 * it + 1];                        \
            __bf16 a0 = (__bf16)v0; float ra = v0 - (float)a0;                 \
            __bf16 a1 = (__bf16)ra; ra -= (float)a1;                           \
            __bf16 a2 = (__bf16)ra;                                            \
            __bf16 b0 = (__bf16)v1; float rb = v1 - (float)b0;                 \
            __bf16 b1 = (__bf16)rb; rb -= (float)b1;                           \
            __bf16 b2 = (__bf16)rb;                                            \
            U2 u0, u1, u2;                                                     \
            u0.h[0] = a0; u0.h[1] = b0;                                        \
            u1.h[0] = a1; u1.h[1] = b1;                                        \
            u2.h[0] = a2; u2.h[1] = b2;                                        \
            xsp[BUF][0][h * 36 + cp] = u0.u;                                   \
            xsp[BUF][1][h * 36 + cp] = u1.u;                                   \
            xsp[BUF][2][h * 36 + cp] = u2.u;                                   \
            xxa += v0 * v0 + v1 * v1;                                          \
        }                                                                      \
        xxp[BUF][h][cp0] = xxa;                                                \
    }

// Block: 256 threads = 4 waves; TWO 32-vector tiles per block (1024 blocks).
// Per tile: 32 vectors x 512 codes; wave ni owns a 128-code quarter,
// 2x8 MFMA 16x16 tiles, acc[2][8] = 64 AGPR. Tile1's global loads are issued
// before tile0's compute (T14 async stage); split-build lands in LDS buf1
// during tile0's tail.
__global__ __launch_bounds__(256, 4)
void k1_main(const float* __restrict__ in, const float* __restrict__ emb,
             float* __restrict__ out, float* __restrict__ wsf) {
    __shared__ unsigned int xsp[2][3][32 * 36]; // double-buffered bf16 splits
    __shared__ float xxp[2][32][9];             // per-thread ||x||^2 partials
    __shared__ float pmin[4][32];
    __shared__ int   pidx[4][32];
    __shared__ float xxs[32];
    __shared__ int   hist[K_CODES];

    const int t    = threadIdx.x;
    const int lane = t & 63;
    const int wave = t >> 6;           // 0..3
    const int ni   = wave;             // 128-code quarter
    const int col  = lane & 15;
    const int quad = lane >> 4;
    const int h    = t & 31;
    const int cp0  = t >> 5;

    hist[t] = 0; hist[t + 256] = 0;

    const int blk = blockIdx.x;                        // 0..1023
    const int rep = blk & (NREP - 1);                  // atomic replica

    // Stage tile0 + build its splits
    {
        const int g0 = blk * 2;
        const float* xb = in + (g0 >> 5) * (DIM * HW) + (g0 & 31) * 32;
        float sv[8];
        #pragma unroll
        for (int it = 0; it < 4; ++it) {
            int cp = it * 8 + cp0;
            sv[2 * it]     = xb[(2 * cp) * HW + h];
            sv[2 * it + 1] = xb[(2 * cp + 1) * HW + h];
        }
        BUILD_SPLITS(sv, 0)
    }

    // Issue tile1's global loads NOW (latency hides under tile0 compute)
    float sv1[8];
    {
        const int g1 = blk * 2 + 1;
        const float* xb = in + (g1 >> 5) * (DIM * HW) + (g1 & 31) * 32;
        #pragma unroll
        for (int it = 0; it < 4; ++it) {
            int cp = it * 8 + cp0;
            sv1[2 * it]     = xb[(2 * cp) * HW + h];
            sv1[2 * it + 1] = xb[(2 * cp + 1) * HW + h];
        }
    }
    __syncthreads();

    const bf16x8* bp8 = (const bf16x8*)(wsf + WS_BP);

    #pragma unroll 1
    for (int tl = 0; tl < 2; ++tl) {
        const int gtile   = blk * 2 + tl;
        const int n_img   = gtile >> 5;
        const int hw_base = (gtile & 31) * 32;

        // Accumulators init with ||e||^2 (d = ee - 2<x,e>)
        f32x4 acc[2][8];
        #pragma unroll
        for (int nt = 0; nt < 8; ++nt) {
            float eev = wsf[WS_EE + ni * 128 + nt * 16 + col];
            #pragma unroll
            for (int mi = 0; mi < 2; ++mi) {
                acc[mi][nt][0] = eev; acc[mi][nt][1] = eev;
                acc[mi][nt][2] = eev; acc[mi][nt][3] = eev;
            }
        }

        // ||x||^2 per vector (read later, post-sync)
        if (t < 32) {
            float s = 0.0f;
            #pragma unroll
            for (int j = 0; j < 8; ++j) s += xxp[tl][t][j];
            xxs[t] = s;
        }

        // A fragments
        bf16x8 Af[2][3][2];                              // [ks][split][mi]
        #pragma unroll
        for (int ks = 0; ks < 2; ++ks)
            #pragma unroll
            for (int mi = 0; mi < 2; ++mi) {
                int u = (mi * 16 + col) * 36 + ks * 16 + quad * 4;
                Af[ks][0][mi] = *(const bf16x8*)&xsp[tl][0][u];
                Af[ks][1][mi] = *(const bf16x8*)&xsp[tl][1][u];
                Af[ks][2][mi] = *(const bf16x8*)&xsp[tl][2][u];
            }

        // 12-phase pipeline: p = (ks=p/6, s=(p%6)/2, bh=p&1); 2-deep B prefetch.
        bf16x8 Bp[3][4];
        #pragma unroll
        for (int n4 = 0; n4 < 4; ++n4)
            Bp[0][n4] = bp8[(((ni * 8 + n4) * 2 + 0) * 64) + lane];
        #pragma unroll
        for (int n4 = 0; n4 < 4; ++n4)
            Bp[1][n4] = bp8[(((ni * 8 + 4 + n4) * 2 + 0) * 64) + lane];

        #pragma unroll
        for (int p = 0; p < 12; ++p) {
            const int ks = p / 6, s = (p % 6) / 2, bh = p & 1;
            if (p < 10) {
                const int pn = p + 2;
                const int ksn = pn / 6, sn = (pn % 6) / 2, bhn = pn & 1;
                #pragma unroll
                for (int n4 = 0; n4 < 4; ++n4)
                    Bp[pn % 3][n4] = bp8[(((sn * 32 + ni * 8 + bhn * 4 + n4) * 2 + ksn) * 64) + lane];
            }
            #pragma unroll
            for (int mi = 0; mi < 2; ++mi)
                #pragma unroll
                for (int n4 = 0; n4 < 4; ++n4)
                    acc[mi][bh * 4 + n4] = __builtin_amdgcn_mfma_f32_16x16x32_bf16(
                        Af[ks][0][mi], Bp[p % 3][n4], acc[mi][bh * 4 + n4], 0, 0, 0);
            if (s < 2) {
                #pragma unroll
                for (int mi = 0; mi < 2; ++mi)
                    #pragma unroll
                    for (int n4 = 0; n4 < 4; ++n4)
                        acc[mi][bh * 4 + n4] = __builtin_amdgcn_mfma_f32_16x16x32_bf16(
                            Af[ks][1][mi], Bp[p % 3][n4], acc[mi][bh * 4 + n4], 0, 0, 0);
            }
            if (s == 0) {
                #pragma unroll
                for (int mi = 0; mi < 2; ++mi)
                    #pragma unroll
                    for (int n4 = 0; n4 < 4; ++n4)
                        acc[mi][bh * 4 + n4] = __builtin_amdgcn_mfma_f32_16x16x32_bf16(
                            Af[ks][2][mi], Bp[p % 3][n4], acc[mi][bh * 4 + n4], 0, 0, 0);
            }
        }

        // Argmin. C layout: col(code) = lane&15, row(vector) = quad*4 + reg.
        #pragma unroll
        for (int mi = 0; mi < 2; ++mi) {
            #pragma unroll
            for (int r = 0; r < 4; ++r) {
                float v  = acc[mi][0][r];
                int   bi = ni * 128 + col;
                #pragma unroll
                for (int nt = 1; nt < 8; ++nt) {        // ascending codes, strict < = first-min
                    float u  = acc[mi][nt][r];
                    int   ui = ni * 128 + nt * 16 + col;
                    if (u < v) { v = u; bi = ui; }
                }
                #pragma unroll
                for (int off = 1; off < 16; off <<= 1) { // 16-lane butterfly, idx tie-break
                    float ov = __shfl_xor(v, off);
                    int   oi = __shfl_xor(bi, off);
                    if (ov < v || (ov == v && oi < bi)) { v = ov; bi = oi; }
                }
                if (col == 0) {
                    int row = mi * 16 + quad * 4 + r;
                    pmin[ni][row] = v;
                    pidx[ni][row] = bi;
                }
            }
        }
        __syncthreads();

        // Combine the 4 n-quarters (ascending code ranges), then idx/loss/hist
        if (t < 32) {
            float v = pmin[0][t]; int bi = pidx[0][t];
            #pragma unroll
            for (int q = 1; q < 4; ++q) {
                float u = pmin[q][t]; int ui = pidx[q][t];
                if (u < v) { v = u; bi = ui; }
            }
            pidx[0][t] = bi;                             // publish final idx
            out[O3 + gtile * 32 + t] = (float)bi;
            atomicAdd(&hist[bi], 1);
            float ld = v + xxs[t];                       // d_min = xx + (ee - 2<x,e>)
            #pragma unroll
            for (int off = 16; off > 0; off >>= 1) ld += __shfl_down(ld, off);
            if (t == 0) wsf[WS_LOSS + gtile] = ld;       // per-tile loss partial
        }
        __syncthreads();

        // out_q: thread t -> vector v = t&31, c-octant t>>5; coalesced per c-plane
        {
            int v = t & 31, cq = t >> 5;
            int kv = pidx[0][v];
            const float* ew = emb + kv * DIM;
            float* oq = out + O1 + n_img * (DIM * HW) + hw_base + v;
            #pragma unroll
            for (int c = cq * 8; c < cq * 8 + 8; ++c) oq[c * HW] = ew[c];
        }

        // dw: wave w -> rows [w*8, w*8+8); reconstructed from splits (~2^-24 exact)
        {
            float* dwr = wsf + WS_DW + rep * 32768;
            #pragma unroll
            for (int v8 = 0; v8 < 8; ++v8) {
                int v  = wave * 8 + v8;
                int kv = pidx[0][v];
                int wi = v * 36 + (lane >> 1);
                U2 a0, a1, a2;
                a0.u = xsp[tl][0][wi]; a1.u = xsp[tl][1][wi]; a2.u = xsp[tl][2][wi];
                int hs = lane & 1;
                float val = (float)a0.h[hs] + (float)a1.h[hs] + (float)a2.h[hs];
                atomicAdd(&dwr[kv * 64 + lane], val);
            }
        }

        // counts: histogram-compacted atomics, then same-thread hist reset
        int* cnt = (int*)(wsf + WS_CNT);
        if (hist[t])       { atomicAdd(&cnt[rep * 512 + t], hist[t]); hist[t] = 0; }
        if (hist[t + 256]) { atomicAdd(&cnt[rep * 512 + t + 256], hist[t + 256]); hist[t + 256] = 0; }

        if (tl == 0) {
            BUILD_SPLITS(sv1, 1)                         // land tile1 in LDS buf1
            __syncthreads();
        }
    }
}

// Merged epilogue: blocks 0..127 = new_ema_w / new_embedding / new_cs (coalesced);
// block 128 = loss + perplexity.
__global__ void k2(const float* __restrict__ ema_cs, const float* __restrict__ ema_w,
                   float* __restrict__ out, const float* __restrict__ wsf) {
    __shared__ float s1[256], s2[256];
    const int t = threadIdx.x;
    const int blk = blockIdx.x;
    const int* cnt = (const int*)(wsf + WS_CNT);

    if (blk == 128) {
        // loss: sum 2048 per-tile partials
        float ls = 0.0f;
        #pragma unroll
        for (int j = 0; j < 8; ++j) ls += wsf[WS_LOSS + j * 256 + t];
        s1[t] = ls;
        // perplexity from counts
        float ca = 0.0f, cb = 0.0f;
        #pragma unroll
        for (int r = 0; r < NREP; ++r) {
            ca += (float)cnt[r * 512 + t];
            cb += (float)cnt[r * 512 + 256 + t];
        }
        float pa = ca * (1.0f / 65536.0f);
        float pb = cb * (1.0f / 65536.0f);
        s2[t] = pa * logf(pa + 1e-10f) + pb * logf(pb + 1e-10f);
        __syncthreads();
        for (int s = 128; s > 0; s >>= 1) {
            if (t < s) { s1[t] += s1[t + s]; s2[t] += s2[t + s]; }
            __syncthreads();
        }
        if (t == 0) {
            out[O0] = 0.25f * s1[0] * (1.0f / 4194304.0f);
            out[O2] = expf(-s2[0]);
        }
        return;
    }

    const int m = blk * 256 + t;                         // 0..32767
    const int k = m >> 6;
    float ck = 0.0f, dwsum = 0.0f;
    #pragma unroll
    for (int r = 0; r < NREP; ++r) {
        ck    += (float)cnt[r * 512 + k];
        dwsum += wsf[WS_DW + r * 32768 + m];
    }
    float n    = wsf[WS_N];
    float rawk = 0.99f * ema_cs[k] + 0.01f * ck;
    float csk  = (rawk + 1e-5f) / (n + 512.0f * 1e-5f) * n;   // Laplace smoothing
    float wv   = 0.99f * ema_w[m] + 0.01f * dwsum;
    out[O5 + m] = wv;
    out[O6 + m] = wv / csk;
    if ((m & 63) == 0) out[O4 + k] = csk;
}

extern "C" void kernel_launch(void* const* d_in, const int* in_sizes, int n_in,
                              void* d_out, int out_size, void* d_ws, size_t ws_size,
                              hipStream_t stream) {
    const float* in     = (const float*)d_in[0];   // inputs  (64,64,32,32) NCHW
    const float* emb    = (const float*)d_in[1];   // embedding (512,64)
    const float* ema_w  = (const float*)d_in[2];   // ema_w (512,64)
    const float* ema_cs = (const float*)d_in[3];   // ema_cluster_size (512)
    float* out = (float*)d_out;
    float* wsf = (float*)d_ws;

    hipLaunchKernelGGL(k0_init, dim3(899),  dim3(256), 0, stream, emb, ema_cs, wsf);
    hipLaunchKernelGGL(k1_main, dim3(1024), dim3(256), 0, stream, in, emb, out, wsf);
    hipLaunchKernelGGL(k2,      dim3(129),  dim3(256), 0, stream, ema_cs, ema_w, out, wsf);
}